// Round 4
// baseline (129.212 us; speedup 1.0000x reference)
//
#include <hip/hip_runtime.h>
#include <math.h>

static constexpr int NN   = 4096;
static constexpr int INC  = 256;
static constexpr int OUTC = 64;

typedef _Float16 half8 __attribute__((ext_vector_type(8)));
typedef float floatx4 __attribute__((ext_vector_type(4)));

__device__ __forceinline__ float lrelu(float x) {
    return fmaxf(x, 0.f) + 0.2f * fminf(x, 0.f);
}
__device__ __forceinline__ float elu1(float x) {
    return x > 0.f ? x : (__expf(x) - 1.f);
}

// K0: pack adj (64 MB int32) -> bitmask (2 MB), j-order: bits[b] bit i == adj[8b+i]>0.
// Each thread: 32 consecutive ints (8x int4, lane-private 128B line) -> one u32 store.
// Dense streaming read at full HBM BW; 2048 blocks = 32 waves/CU.
__global__ __launch_bounds__(256) void k_pack(const int* __restrict__ adj,
                                              unsigned int* __restrict__ bits) {
    const int tau = blockIdx.x * 256 + threadIdx.x;      // 0..524287
    const int4* src = (const int4*)adj + (size_t)tau * 8;
    unsigned int out = 0;
    #pragma unroll
    for (int u = 0; u < 8; ++u) {
        const int4 v = src[u];
        const unsigned int nib = (unsigned int)(v.x > 0)
                               | ((unsigned int)(v.y > 0) << 1)
                               | ((unsigned int)(v.z > 0) << 2)
                               | ((unsigned int)(v.w > 0) << 3);
        out |= nib << (4 * u);
    }
    bits[tau] = out;
}

// K1: Wh = H@W; store WhT as fp16 transposed (64 x 4096); f1 = Wh@a1; f2 = Wh@a2.
__global__ __launch_bounds__(256) void k_wh(const float* __restrict__ H,
                                            const float* __restrict__ W,
                                            const float* __restrict__ a,
                                            unsigned short* __restrict__ WhT,
                                            float* __restrict__ f1,
                                            float* __restrict__ f2) {
    __shared__ __align__(16) float Wl[INC * OUTC];   // 64 KB
    __shared__ __align__(16) float Hl[16 * INC];     // 16 KB
    __shared__ _Float16 Tl[16 * 68];                 // transpose buffer (pad 68)
    const int t = threadIdx.x;
    const int i0 = blockIdx.x * 16;
    {
        const float4* W4 = (const float4*)W;
        float4* Wl4 = (float4*)Wl;
        #pragma unroll
        for (int u = 0; u < 16; ++u) Wl4[u * 256 + t] = W4[u * 256 + t];
        const float4* H4 = (const float4*)(H + i0 * INC);
        float4* Hl4 = (float4*)Hl;
        #pragma unroll
        for (int u = 0; u < 4; ++u) Hl4[u * 256 + t] = H4[u * 256 + t];
    }
    __syncthreads();
    const int c = t & 63;       // channel (lane)
    const int g = t >> 6;       // wave -> row group
    const float a1c = a[c];
    const float a2c = a[OUTC + c];
    float acc[4] = {0.f, 0.f, 0.f, 0.f};
    const float4* Hl4 = (const float4*)Hl;
    for (int k4 = 0; k4 < INC / 4; ++k4) {
        const float w0 = Wl[(k4 * 4 + 0) * OUTC + c];
        const float w1 = Wl[(k4 * 4 + 1) * OUTC + c];
        const float w2 = Wl[(k4 * 4 + 2) * OUTC + c];
        const float w3 = Wl[(k4 * 4 + 3) * OUTC + c];
        #pragma unroll
        for (int s = 0; s < 4; ++s) {
            const float4 h = Hl4[(g + 4 * s) * (INC / 4) + k4];
            acc[s] = fmaf(h.x, w0, fmaf(h.y, w1, fmaf(h.z, w2, fmaf(h.w, w3, acc[s]))));
        }
    }
    #pragma unroll
    for (int s = 0; s < 4; ++s) {
        const int r = g + 4 * s;
        Tl[r * 68 + c] = (_Float16)acc[s];
        float v1 = acc[s] * a1c;
        float v2 = acc[s] * a2c;
        #pragma unroll
        for (int off = 32; off; off >>= 1) {
            v1 += __shfl_xor(v1, off);
            v2 += __shfl_xor(v2, off);
        }
        if (c == 0) { f1[i0 + r] = v1; f2[i0 + r] = v2; }
    }
    __syncthreads();
    const int c2 = t >> 2;
    const int rs = (t & 3) * 4;
    ushort4 u;
    u.x = *(const unsigned short*)&Tl[(rs + 0) * 68 + c2];
    u.y = *(const unsigned short*)&Tl[(rs + 1) * 68 + c2];
    u.z = *(const unsigned short*)&Tl[(rs + 2) * 68 + c2];
    u.w = *(const unsigned short*)&Tl[(rs + 3) * 68 + c2];
    *(ushort4*)(WhT + c2 * NN + i0 + rs) = u;
}

// K2: fused attention, 16 rows x all 4096 j per block, 16 waves.
// adj mask comes from the 2 MB bitmask (1 byte per lane-iter, L2-resident).
__global__ __launch_bounds__(1024, 4) void k_att(const unsigned char* __restrict__ bits,
                                                 const _Float16* __restrict__ WhT,
                                                 const float* __restrict__ f1,
                                                 const float* __restrict__ f2,
                                                 float* __restrict__ out) {
    __shared__ __align__(16) float sf2[NN];         // 16 KB
    __shared__ __align__(16) float sacc[16 * 1024]; // 64 KB
    __shared__ float sden[16 * 16];
    __shared__ float smax[16];
    const int t = threadIdx.x;
    const int w = t >> 6;          // wave 0..15
    const int l = t & 63;
    const int m = l & 15;          // A row (= output row within tile)
    const int quad = l >> 4;       // k-group
    const int i0 = blockIdx.x * 16;

    // pre-pass: f2 -> LDS, block max
    {
        const float4 v = ((const float4*)f2)[t];
        ((float4*)sf2)[t] = v;
        float mloc = fmaxf(fmaxf(v.x, v.y), fmaxf(v.z, v.w));
        #pragma unroll
        for (int off = 32; off; off >>= 1) mloc = fmaxf(mloc, __shfl_xor(mloc, off));
        if (l == 0) smax[w] = mloc;
    }
    __syncthreads();
    float maxf2 = smax[0];
    #pragma unroll
    for (int k = 1; k < 16; ++k) maxf2 = fmaxf(maxf2, smax[k]);

    const float f1r = f1[i0 + m];
    const float mrow = lrelu(f1r + maxf2);  // exact per-row softmax max (lrelu monotone)
    float den = 0.f;
    floatx4 acc[4] = {{0.f,0.f,0.f,0.f},{0.f,0.f,0.f,0.f},{0.f,0.f,0.f,0.f},{0.f,0.f,0.f,0.f}};
    const int jbase = w * 32 + quad * 8;
    // prefetch this lane's 8 mask bytes (row i0+m, bytes jbase/8 + it*64)
    const unsigned char* brow = bits + (size_t)(i0 + m) * (NN / 8) + (jbase >> 3);
    unsigned int m8[8];
    #pragma unroll
    for (int it = 0; it < 8; ++it) m8[it] = brow[it * 64];

    #pragma unroll 2
    for (int it = 0; it < 8; ++it) {
        const int j = jbase + it * 512;
        const unsigned int mb = m8[it];
        const float4 g0 = *(const float4*)(sf2 + j);
        const float4 g1 = *(const float4*)(sf2 + j + 4);
        half8 af;
        {
            float p;
            p = __expf(lrelu(f1r + g0.x) - mrow); den += p; af[0] = (mb & 1u)   ? (_Float16)p : (_Float16)0.f;
            p = __expf(lrelu(f1r + g0.y) - mrow); den += p; af[1] = (mb & 2u)   ? (_Float16)p : (_Float16)0.f;
            p = __expf(lrelu(f1r + g0.z) - mrow); den += p; af[2] = (mb & 4u)   ? (_Float16)p : (_Float16)0.f;
            p = __expf(lrelu(f1r + g0.w) - mrow); den += p; af[3] = (mb & 8u)   ? (_Float16)p : (_Float16)0.f;
            p = __expf(lrelu(f1r + g1.x) - mrow); den += p; af[4] = (mb & 16u)  ? (_Float16)p : (_Float16)0.f;
            p = __expf(lrelu(f1r + g1.y) - mrow); den += p; af[5] = (mb & 32u)  ? (_Float16)p : (_Float16)0.f;
            p = __expf(lrelu(f1r + g1.z) - mrow); den += p; af[6] = (mb & 64u)  ? (_Float16)p : (_Float16)0.f;
            p = __expf(lrelu(f1r + g1.w) - mrow); den += p; af[7] = (mb & 128u) ? (_Float16)p : (_Float16)0.f;
        }
        #pragma unroll
        for (int nt = 0; nt < 4; ++nt) {
            const half8 bf = *(const half8*)(WhT + (size_t)(nt * 16 + m) * NN + j);
            acc[nt] = __builtin_amdgcn_mfma_f32_16x16x32_f16(af, bf, acc[nt], 0, 0, 0);
        }
    }
    // den: lanes {m, m+16, m+32, m+48} hold partials for row m
    den += __shfl_xor(den, 16);
    den += __shfl_xor(den, 32);
    if (l < 16) sden[w * 16 + l] = den;
    // D layout (verified R2): out row = quad*4 + reg, channel = nt*16 + (lane&15)
    #pragma unroll
    for (int nt = 0; nt < 4; ++nt)
        #pragma unroll
        for (int r = 0; r < 4; ++r)
            sacc[w * 1024 + (quad * 4 + r) * 64 + nt * 16 + m] = acc[nt][r];
    __syncthreads();
    // epilogue: thread t owns output (row = t>>6, ch = t&63) of this 16x64 tile
    float s = 0.f;
    #pragma unroll
    for (int w2 = 0; w2 < 16; ++w2) s += sacc[w2 * 1024 + t];
    float dden = 0.f;
    const int row = t >> 6;
    #pragma unroll
    for (int w2 = 0; w2 < 16; ++w2) dden += sden[w2 * 16 + row];
    out[(size_t)i0 * OUTC + t] = elu1(s / dden);
}

extern "C" void kernel_launch(void* const* d_in, const int* in_sizes, int n_in,
                              void* d_out, int out_size, void* d_ws, size_t ws_size,
                              hipStream_t stream) {
    const float* H  = (const float*)d_in[0];
    const int* adj  = (const int*)d_in[1];
    const float* W  = (const float*)d_in[2];
    const float* a  = (const float*)d_in[3];
    float* out = (float*)d_out;
    char* ws = (char*)d_ws;
    // ws: WhT 512K | f1 16K | f2 16K | bits 2M @ 1M
    unsigned short* WhT = (unsigned short*)(ws);
    float* f1 = (float*)(ws + (512 << 10));
    float* f2 = (float*)(ws + (528 << 10));
    unsigned int* bits = (unsigned int*)(ws + (1 << 20));
    hipLaunchKernelGGL(k_pack, dim3(2048), dim3(256), 0, stream, adj, bits);
    hipLaunchKernelGGL(k_wh,   dim3(256),  dim3(256), 0, stream, H, W, a, WhT, f1, f2);
    hipLaunchKernelGGL(k_att,  dim3(256),  dim3(1024), 0, stream,
                       (const unsigned char*)bits, (const _Float16*)WhT, f1, f2, out);
}

// Round 5
// 123.387 us; speedup vs baseline: 1.0472x; 1.0472x over previous
//
#include <hip/hip_runtime.h>
#include <math.h>

static constexpr int NN   = 4096;
static constexpr int INC  = 256;
static constexpr int OUTC = 64;

typedef _Float16 half8 __attribute__((ext_vector_type(8)));
typedef float floatx4 __attribute__((ext_vector_type(4)));

__device__ __forceinline__ float lrelu(float x) {
    return fmaxf(x, 0.f) + 0.2f * fminf(x, 0.f);
}
__device__ __forceinline__ float elu1(float x) {
    return x > 0.f ? x : (__expf(x) - 1.f);
}

// K_prep: fused independent front-end work, one launch.
//  - blocks 0..255   : Wh = H@W -> fp16 WhT (transposed), f1 = Wh@a1, f2 = Wh@a2
//                      (W read straight from L2, coalesced; LDS only 18.5 KB so
//                       pack blocks co-resident on the same CUs keep HBM saturated)
//  - blocks 256..2303: pack adj (64 MB) -> 2 MB bitmask, dense streaming read.
__global__ __launch_bounds__(256) void k_prep(const int* __restrict__ adj,
                                              unsigned int* __restrict__ bits,
                                              const float* __restrict__ H,
                                              const float* __restrict__ W,
                                              const float* __restrict__ a,
                                              unsigned short* __restrict__ WhT,
                                              float* __restrict__ f1,
                                              float* __restrict__ f2) {
    const int t = threadIdx.x;
    if (blockIdx.x >= 256) {
        // ---- pack branch ----
        const int tau = (blockIdx.x - 256) * 256 + t;        // 0..524287
        const int4* src = (const int4*)adj + (size_t)tau * 8;
        unsigned int o = 0;
        #pragma unroll
        for (int u = 0; u < 8; ++u) {
            const int4 v = src[u];
            const unsigned int nib = (unsigned int)(v.x > 0)
                                   | ((unsigned int)(v.y > 0) << 1)
                                   | ((unsigned int)(v.z > 0) << 2)
                                   | ((unsigned int)(v.w > 0) << 3);
            o |= nib << (4 * u);
        }
        bits[tau] = o;
        return;
    }
    // ---- wh branch ----
    __shared__ __align__(16) float Hl[16 * INC];   // 16 KB
    __shared__ _Float16 Tl[16 * 68];               // 2.2 KB transpose buffer
    const int i0 = blockIdx.x * 16;
    {
        const float4* H4 = (const float4*)(H + i0 * INC);
        float4* Hl4 = (float4*)Hl;
        #pragma unroll
        for (int u = 0; u < 4; ++u) Hl4[u * 256 + t] = H4[u * 256 + t];
    }
    __syncthreads();
    const int c = t & 63;       // channel (lane)
    const int g = t >> 6;       // wave -> row group
    const float a1c = a[c];
    const float a2c = a[OUTC + c];
    float acc[4] = {0.f, 0.f, 0.f, 0.f};
    const float4* Hl4 = (const float4*)Hl;
    #pragma unroll 4
    for (int k4 = 0; k4 < INC / 4; ++k4) {
        const float w0 = W[(k4 * 4 + 0) * OUTC + c];   // coalesced, L2-hit
        const float w1 = W[(k4 * 4 + 1) * OUTC + c];
        const float w2 = W[(k4 * 4 + 2) * OUTC + c];
        const float w3 = W[(k4 * 4 + 3) * OUTC + c];
        #pragma unroll
        for (int s = 0; s < 4; ++s) {
            const float4 h = Hl4[(g + 4 * s) * (INC / 4) + k4];
            acc[s] = fmaf(h.x, w0, fmaf(h.y, w1, fmaf(h.z, w2, fmaf(h.w, w3, acc[s]))));
        }
    }
    #pragma unroll
    for (int s = 0; s < 4; ++s) {
        const int r = g + 4 * s;
        Tl[r * 68 + c] = (_Float16)acc[s];
        float v1 = acc[s] * a1c;
        float v2 = acc[s] * a2c;
        #pragma unroll
        for (int off = 32; off; off >>= 1) {
            v1 += __shfl_xor(v1, off);
            v2 += __shfl_xor(v2, off);
        }
        if (c == 0) { f1[i0 + r] = v1; f2[i0 + r] = v2; }
    }
    __syncthreads();
    const int c2 = t >> 2;
    const int rs = (t & 3) * 4;
    ushort4 u;
    u.x = *(const unsigned short*)&Tl[(rs + 0) * 68 + c2];
    u.y = *(const unsigned short*)&Tl[(rs + 1) * 68 + c2];
    u.z = *(const unsigned short*)&Tl[(rs + 2) * 68 + c2];
    u.w = *(const unsigned short*)&Tl[(rs + 3) * 68 + c2];
    *(ushort4*)(WhT + c2 * NN + i0 + rs) = u;
}

// K_att: fused attention, 16 rows x all 4096 j per block, 16 waves.
// adj mask from the 2 MB bitmask (L2-resident, 1 byte per lane-iter).
__global__ __launch_bounds__(1024, 4) void k_att(const unsigned char* __restrict__ bits,
                                                 const _Float16* __restrict__ WhT,
                                                 const float* __restrict__ f1,
                                                 const float* __restrict__ f2,
                                                 float* __restrict__ out) {
    __shared__ __align__(16) float sf2[NN];         // 16 KB
    __shared__ __align__(16) float sacc[16 * 1024]; // 64 KB
    __shared__ float sden[16 * 16];
    __shared__ float smax[16];
    const int t = threadIdx.x;
    const int w = t >> 6;          // wave 0..15
    const int l = t & 63;
    const int m = l & 15;          // A row (= output row within tile)
    const int quad = l >> 4;       // k-group
    const int i0 = blockIdx.x * 16;

    // pre-pass: f2 -> LDS, block max
    {
        const float4 v = ((const float4*)f2)[t];
        ((float4*)sf2)[t] = v;
        float mloc = fmaxf(fmaxf(v.x, v.y), fmaxf(v.z, v.w));
        #pragma unroll
        for (int off = 32; off; off >>= 1) mloc = fmaxf(mloc, __shfl_xor(mloc, off));
        if (l == 0) smax[w] = mloc;
    }
    __syncthreads();
    float maxf2 = smax[0];
    #pragma unroll
    for (int k = 1; k < 16; ++k) maxf2 = fmaxf(maxf2, smax[k]);

    const float f1r = f1[i0 + m];
    const float mrow = lrelu(f1r + maxf2);  // exact per-row softmax max (lrelu monotone)
    float den = 0.f;
    floatx4 acc[4] = {{0.f,0.f,0.f,0.f},{0.f,0.f,0.f,0.f},{0.f,0.f,0.f,0.f},{0.f,0.f,0.f,0.f}};
    const int jbase = w * 32 + quad * 8;
    const unsigned char* brow = bits + (size_t)(i0 + m) * (NN / 8) + (jbase >> 3);
    unsigned int m8[8];
    #pragma unroll
    for (int it = 0; it < 8; ++it) m8[it] = brow[it * 64];

    #pragma unroll 2
    for (int it = 0; it < 8; ++it) {
        const int j = jbase + it * 512;
        const unsigned int mb = m8[it];
        const float4 g0 = *(const float4*)(sf2 + j);
        const float4 g1 = *(const float4*)(sf2 + j + 4);
        half8 af;
        {
            float p;
            p = __expf(lrelu(f1r + g0.x) - mrow); den += p; af[0] = (mb & 1u)   ? (_Float16)p : (_Float16)0.f;
            p = __expf(lrelu(f1r + g0.y) - mrow); den += p; af[1] = (mb & 2u)   ? (_Float16)p : (_Float16)0.f;
            p = __expf(lrelu(f1r + g0.z) - mrow); den += p; af[2] = (mb & 4u)   ? (_Float16)p : (_Float16)0.f;
            p = __expf(lrelu(f1r + g0.w) - mrow); den += p; af[3] = (mb & 8u)   ? (_Float16)p : (_Float16)0.f;
            p = __expf(lrelu(f1r + g1.x) - mrow); den += p; af[4] = (mb & 16u)  ? (_Float16)p : (_Float16)0.f;
            p = __expf(lrelu(f1r + g1.y) - mrow); den += p; af[5] = (mb & 32u)  ? (_Float16)p : (_Float16)0.f;
            p = __expf(lrelu(f1r + g1.z) - mrow); den += p; af[6] = (mb & 64u)  ? (_Float16)p : (_Float16)0.f;
            p = __expf(lrelu(f1r + g1.w) - mrow); den += p; af[7] = (mb & 128u) ? (_Float16)p : (_Float16)0.f;
        }
        #pragma unroll
        for (int nt = 0; nt < 4; ++nt) {
            const half8 bf = *(const half8*)(WhT + (size_t)(nt * 16 + m) * NN + j);
            acc[nt] = __builtin_amdgcn_mfma_f32_16x16x32_f16(af, bf, acc[nt], 0, 0, 0);
        }
    }
    den += __shfl_xor(den, 16);
    den += __shfl_xor(den, 32);
    if (l < 16) sden[w * 16 + l] = den;
    // D layout (verified R2): out row = quad*4 + reg, channel = nt*16 + (lane&15)
    #pragma unroll
    for (int nt = 0; nt < 4; ++nt)
        #pragma unroll
        for (int r = 0; r < 4; ++r)
            sacc[w * 1024 + (quad * 4 + r) * 64 + nt * 16 + m] = acc[nt][r];
    __syncthreads();
    float s = 0.f;
    #pragma unroll
    for (int w2 = 0; w2 < 16; ++w2) s += sacc[w2 * 1024 + t];
    float dden = 0.f;
    const int row = t >> 6;
    #pragma unroll
    for (int w2 = 0; w2 < 16; ++w2) dden += sden[w2 * 16 + row];
    out[(size_t)i0 * OUTC + t] = elu1(s / dden);
}

extern "C" void kernel_launch(void* const* d_in, const int* in_sizes, int n_in,
                              void* d_out, int out_size, void* d_ws, size_t ws_size,
                              hipStream_t stream) {
    const float* H  = (const float*)d_in[0];
    const int* adj  = (const int*)d_in[1];
    const float* W  = (const float*)d_in[2];
    const float* a  = (const float*)d_in[3];
    float* out = (float*)d_out;
    char* ws = (char*)d_ws;
    // ws: WhT 512K | f1 16K | f2 16K | bits 2M @ 1M
    unsigned short* WhT = (unsigned short*)(ws);
    float* f1 = (float*)(ws + (512 << 10));
    float* f2 = (float*)(ws + (528 << 10));
    unsigned int* bits = (unsigned int*)(ws + (1 << 20));
    hipLaunchKernelGGL(k_prep, dim3(2304), dim3(256), 0, stream,
                       adj, bits, H, W, a, WhT, f1, f2);
    hipLaunchKernelGGL(k_att,  dim3(256),  dim3(1024), 0, stream,
                       (const unsigned char*)bits, (const _Float16*)WhT, f1, f2, out);
}